// Round 10
// baseline (228.970 us; speedup 1.0000x reference)
//
#include <hip/hip_runtime.h>
#include <stdint.h>

// CrossAttentionHead: B=8, C=768, S=T=2304, D=512.
// transpose/cvt -> qkv8 (256^2 8-phase, BK=32, 2 blocks/CU) ->
// scores8 (same, exp epilogue + atomic row denom) ->
// pv8 (BK=64, NT=36, 1/denom fp32 epilogue).
// Round-10: BK templated. BK=32 halves LDS to 64KB -> 2 blocks/CU for
// scores/qkv (cross-block overlap hides barrier stalls; tail halves).
// Ledger identical; vmcnt rescaled: loads/stage 1 -> gates = vmcnt(2).
//
// Workspace (ushort elems):
//   Q[0,..) K[9437184,..) Vt[18874368,..)  (each 9,437,184)
//   P@28311552 (42,467,328 elems, 85MB); aliased inside P (dead before P):
//   xs@28311552, xts@42467328, wcat@56623104 (wq|wk|wv, 1536x768),
//   bcat(f32)@ushort 57802752; denom(f32,18432)@ushort 70778880.

typedef __bf16 bf16x8 __attribute__((ext_vector_type(8)));
typedef float f32x4 __attribute__((ext_vector_type(4)));

__device__ __forceinline__ unsigned short f2bf(float f) {
  union { float f; unsigned int u; } c; c.f = f;
  return (unsigned short)((c.u + 0x7fffu + ((c.u >> 16) & 1u)) >> 16); // RNE
}

#define GLOAD(gp, lp)                                                          \
  __builtin_amdgcn_global_load_lds(                                            \
      (const __attribute__((address_space(1))) void*)(gp),                     \
      (__attribute__((address_space(3))) void*)(lp), 16, 0, 0)

// ---- all three weights fp32 -> bf16 into contiguous wcat ----
__global__ __launch_bounds__(256) void convw3_kernel(const float* __restrict__ wq,
                                                     const float* __restrict__ wk,
                                                     const float* __restrict__ wv,
                                                     unsigned short* __restrict__ wcat) {
  int i = (blockIdx.x * 256 + threadIdx.x) * 4;
  const float* src = (i < 393216) ? wq : (i < 786432) ? wk : wv;
  const int off = (i < 393216) ? 0 : (i < 786432) ? 393216 : 786432;
  const float4 v = *reinterpret_cast<const float4*>(src + (i - off));
  wcat[i + 0] = f2bf(v.x); wcat[i + 1] = f2bf(v.y);
  wcat[i + 2] = f2bf(v.z); wcat[i + 3] = f2bf(v.w);
}

// ---- zero denom + concat bias ----
__global__ __launch_bounds__(256) void init_kernel(const float* __restrict__ bq,
                                                   const float* __restrict__ bk,
                                                   const float* __restrict__ bv,
                                                   float* __restrict__ denom,
                                                   float* __restrict__ bcat) {
  int i = blockIdx.x * 256 + threadIdx.x;
  if (i < 18432) denom[i] = 0.0f;
  else if (i < 19968) {
    int k = i - 18432;
    bcat[k] = (k < 512) ? bq[k] : (k < 1024) ? bk[k - 512] : bv[k - 1024];
  }
}

// ---- x[b][c][s] fp32 -> xs[b][s][c] bf16 (64x64 LDS tiles) ----
__global__ __launch_bounds__(256) void transpose_bf16_kernel(
    const float* __restrict__ x, const float* __restrict__ xt,
    unsigned short* __restrict__ xs, unsigned short* __restrict__ xts) {
  const int S = 2304, C = 768;
  const int z = blockIdx.z;
  const float* src = (z < 8) ? x : xt;
  unsigned short* dst = (z < 8) ? xs : xts;
  const int b = z & 7;
  src += (size_t)b * C * S;
  dst += (size_t)b * S * C;
  __shared__ float tile[64][65];
  const int s0 = blockIdx.x * 64, c0 = blockIdx.y * 64;
  const int ls = threadIdx.x & 63, lr = threadIdx.x >> 6;
#pragma unroll
  for (int i = 0; i < 16; ++i) {
    const int c = lr + i * 4;
    tile[c][ls] = src[(size_t)(c0 + c) * S + s0 + ls];
  }
  __syncthreads();
#pragma unroll
  for (int i = 0; i < 16; ++i) {
    const int s = lr + i * 4;
    dst[(size_t)(s0 + s) * C + c0 + ls] = f2bf(tile[ls][s]);
  }
}

// ================= 8-phase 256x256 GEMM-BT core (BK templated) =============
// LDS regions (128 rows x BK cols x 2B each): idx = dbuf*4 + side*2 + half.
// Swizzle (both sides): 16B-slot s at row r holds global chunk s^(r&(NC-1)).

template <int BK>
__device__ __forceinline__ void stage_half8(
    unsigned short* __restrict__ lds, const unsigned short* __restrict__ gb,
    int ldg, int tK, int side, int h, int tid) {
  constexpr int NC = BK / 8;  // 16B chunks per row
  const int row = tid / NC;
  const int sw = ((tid % NC) ^ (row & (NC - 1))) * 8;
  unsigned short* l0 = lds + (size_t)((tK & 1) * 4 + side * 2 + h) * (BK * 128);
  const unsigned short* g = gb + (size_t)(h * 128 + row) * ldg + tK * BK + sw;
  GLOAD(g, l0 + (size_t)tid * 8);
  if constexpr (NC == 8) {
    GLOAD(g + (size_t)64 * ldg, l0 + (size_t)(tid + 512) * 8);
  }
}

#define RDB(base, rh, cbv)                                       \
  (*reinterpret_cast<const bf16x8*>(                             \
      reinterpret_cast<const char*>(lds) + (base) + (rh) * (2 * BK) + (cbv)))

#define PH_READ_A(ABASE, HOFF)                             \
  _Pragma("unroll") for (int mf = 0; mf < 4; ++mf)         \
  _Pragma("unroll") for (int kk = 0; kk < KS; ++kk)        \
      a[mf][kk] = RDB(ABASE, (HOFF) + mf * 16 + fr, cb[kk]);
#define PH_READ_B(BF, BBASE, HOFF)                         \
  _Pragma("unroll") for (int nf = 0; nf < 2; ++nf)         \
  _Pragma("unroll") for (int kk = 0; kk < KS; ++kk)        \
      BF[nf][kk] = RDB(BBASE, brh + (HOFF) + nf * 16, cb[kk]);

#define BARRIER_MFMA(MB, NB, BF)                                       \
  __builtin_amdgcn_s_barrier();                                        \
  asm volatile("s_waitcnt lgkmcnt(0)" ::: "memory");                   \
  __builtin_amdgcn_sched_barrier(0);                                   \
  __builtin_amdgcn_s_setprio(1);                                       \
  _Pragma("unroll") for (int mf = 0; mf < 4; ++mf)                     \
  _Pragma("unroll") for (int kk = 0; kk < KS; ++kk) {                  \
    acc[MB + mf][NB + 0] = __builtin_amdgcn_mfma_f32_16x16x32_bf16(    \
        a[mf][kk], BF[0][kk], acc[MB + mf][NB + 0], 0, 0, 0);          \
    acc[MB + mf][NB + 1] = __builtin_amdgcn_mfma_f32_16x16x32_bf16(    \
        a[mf][kk], BF[1][kk], acc[MB + mf][NB + 1], 0, 0, 0);          \
  }                                                                    \
  __builtin_amdgcn_s_setprio(0);                                       \
  __builtin_amdgcn_s_barrier();

#define WAIT_GATE()                                                    \
  if constexpr (BK == 64) asm volatile("s_waitcnt vmcnt(4)" ::: "memory"); \
  else asm volatile("s_waitcnt vmcnt(2)" ::: "memory");

template <int NT, int BK>
__device__ __forceinline__ void gemm8_core(
    const unsigned short* __restrict__ Ab, const unsigned short* __restrict__ Bb,
    int lda, int ldb, unsigned short* __restrict__ lds, f32x4 (&acc)[8][4]) {
  constexpr int NC = BK / 8;
  constexpr int KS = BK / 32;
  constexpr int REGB = BK * 256;  // bytes per region
  const int t = threadIdx.x;
  const int lane = t & 63, wid = t >> 6;
  const int wr = wid >> 2, wc = wid & 3;
  const int fr = lane & 15, fq = lane >> 4;
  const int swm = (fr & (NC - 1)) << 4;
  int cb[KS];
#pragma unroll
  for (int kk = 0; kk < KS; ++kk) cb[kk] = ((kk * 4 + fq) * 16) ^ swm;
  const int brh = (wc & 1) * 64 + fr;
  const int aB0 = (0 + wr) * REGB, aB1 = (4 + wr) * REGB;
  const int bB0 = (2 + (wc >> 1)) * REGB, bB1 = (6 + (wc >> 1)) * REGB;

  bf16x8 a[4][KS], b01[2][KS], b23[2][KS];

  // prologue: T0.B0,B1,A0,A1, T1.B0,B1; drain all but last 2 stages
  stage_half8<BK>(lds, Bb, ldb, 0, 1, 0, t);
  stage_half8<BK>(lds, Bb, ldb, 0, 1, 1, t);
  stage_half8<BK>(lds, Ab, lda, 0, 0, 0, t);
  stage_half8<BK>(lds, Ab, lda, 0, 0, 1, t);
  stage_half8<BK>(lds, Bb, ldb, 1, 1, 0, t);
  stage_half8<BK>(lds, Bb, ldb, 1, 1, 1, t);
  WAIT_GATE();
  __builtin_amdgcn_s_barrier();

  const int NI = NT / 2;
#pragma unroll 1
  for (int i = 0; i < NI; ++i) {
    const bool more = (i + 1 < NI);
    const int tu1 = 2 * i + 1, tu2 = 2 * i + 2, tu3 = 2 * i + 3;
    // ---- P1: read B01(u)+A03(u); stage T(2i+1).A0 ----
    PH_READ_B(b01, bB0, 0); PH_READ_A(aB0, 0);
    stage_half8<BK>(lds, Ab, lda, tu1, 0, 0, t);
    BARRIER_MFMA(0, 0, b01);
    // ---- P2: read B23(u); stage T(2i+1).A1 ----
    PH_READ_B(b23, bB0, 32);
    stage_half8<BK>(lds, Ab, lda, tu1, 0, 1, t);
    BARRIER_MFMA(0, 2, b23);
    // ---- P3: read A47(u); stage T(2i+2).B0 ----
    PH_READ_A(aB0, 64);
    if (more) stage_half8<BK>(lds, Bb, ldb, tu2, 1, 0, t);
    BARRIER_MFMA(4, 2, b23);
    // ---- P4: stage T(2i+2).B1; gate tile 2i+1 ----
    if (more) {
      stage_half8<BK>(lds, Bb, ldb, tu2, 1, 1, t);
      WAIT_GATE();
    } else {
      asm volatile("s_waitcnt vmcnt(0)" ::: "memory");
    }
    BARRIER_MFMA(4, 0, b01);
    // ---- P5: read B01(v)+A03(v); stage T(2i+2).A0 ----
    PH_READ_B(b01, bB1, 0); PH_READ_A(aB1, 0);
    if (more) stage_half8<BK>(lds, Ab, lda, tu2, 0, 0, t);
    BARRIER_MFMA(0, 0, b01);
    // ---- P6: read B23(v); stage T(2i+2).A1 ----
    PH_READ_B(b23, bB1, 32);
    if (more) stage_half8<BK>(lds, Ab, lda, tu2, 0, 1, t);
    BARRIER_MFMA(0, 2, b23);
    // ---- P7: read A47(v); stage T(2i+3).B0 ----
    PH_READ_A(aB1, 64);
    if (more) stage_half8<BK>(lds, Bb, ldb, tu3, 1, 0, t);
    BARRIER_MFMA(4, 2, b23);
    // ---- P8: stage T(2i+3).B1; gate tile 2i+2 ----
    if (more) {
      stage_half8<BK>(lds, Bb, ldb, tu3, 1, 1, t);
      WAIT_GATE();
    }
    BARRIER_MFMA(4, 0, b01);
  }
}

// ---- fused QKV projection, 8-phase 256^2, K=768 (NT=24, BK=32) ----
// swizzle: batch = lin&7; within batch, n fastest (wcat panels cycle, A pinned)
__global__ __launch_bounds__(512) void qkv8_kernel(
    const unsigned short* __restrict__ xs, const unsigned short* __restrict__ xts,
    const unsigned short* __restrict__ wcat, const float* __restrict__ bcat,
    unsigned short* __restrict__ Q, unsigned short* __restrict__ K,
    unsigned short* __restrict__ Vt) {
  extern __shared__ unsigned short lds[];
  const int lin = blockIdx.x + 6 * (blockIdx.y + 9 * blockIdx.z);
  const int b = lin & 7, idx = lin >> 3;       // idx in [0,54)
  const int byp = idx / 6, bxp = idx - byp * 6;
  const int m0 = byp * 256, n0 = bxp * 256;
  const int seg = n0 >> 9;
  const unsigned short* Ab =
      ((seg == 0) ? xs : xts) + (size_t)b * 2304 * 768 + (size_t)m0 * 768;
  const unsigned short* Bb = wcat + (size_t)n0 * 768;
  f32x4 acc[8][4] = {};
  gemm8_core<24, 32>(Ab, Bb, 768, 768, lds, acc);

  const int t = threadIdx.x;
  const int lane = t & 63, wid = t >> 6;
  const int wr = wid >> 2, wc = wid & 3;
  const int fr = lane & 15, fq = lane >> 4;
  if (seg < 2) {
    unsigned short* Cp = ((seg == 0) ? Q : K) + (size_t)b * 2304 * 512;
#pragma unroll
    for (int nf = 0; nf < 4; ++nf) {
      const int ng = n0 + wc * 64 + nf * 16 + fr;
      const float bj = bcat[ng];
      const int col = ng - seg * 512;
#pragma unroll
      for (int mf = 0; mf < 8; ++mf) {
        const int rbase = m0 + wr * 128 + mf * 16 + fq * 4;
#pragma unroll
        for (int r = 0; r < 4; ++r)
          Cp[(size_t)(rbase + r) * 512 + col] = f2bf(acc[mf][nf][r] + bj);
      }
    }
  } else {
    unsigned short* Cp = Vt + (size_t)b * 512 * 2304;
#pragma unroll
    for (int nf = 0; nf < 4; ++nf) {
      const int ng = n0 + wc * 64 + nf * 16 + fr;
      const float bj = bcat[ng];
      const int d = ng - 1024;
#pragma unroll
      for (int mf = 0; mf < 8; ++mf) {
        const int tb = m0 + wr * 128 + mf * 16 + fq * 4;
        ushort4 pk;
        pk.x = f2bf(acc[mf][nf][0] + bj);
        pk.y = f2bf(acc[mf][nf][1] + bj);
        pk.z = f2bf(acc[mf][nf][2] + bj);
        pk.w = f2bf(acc[mf][nf][3] + bj);
        *reinterpret_cast<ushort4*>(&Cp[(size_t)d * 2304 + tb]) = pk;
      }
    }
  }
}

// ---- scores, 8-phase 256^2, K=512 (NT=16, BK=32) ----
// swizzle: batch = lin&7; within batch, m (Q panel) fastest, K panel pinned
__global__ __launch_bounds__(512) void scores8_kernel(
    const unsigned short* __restrict__ Qm, const unsigned short* __restrict__ Km,
    float* __restrict__ denom, unsigned short* __restrict__ P) {
  extern __shared__ unsigned short lds[];
  const int lin = blockIdx.x + 9 * (blockIdx.y + 9 * blockIdx.z);
  const int b = lin & 7, idx = lin >> 3;       // idx in [0,81)
  const int bxp = idx / 9, byp = idx - bxp * 9;
  const int m0 = byp * 256, n0 = bxp * 256;
  const unsigned short* Ab = Qm + (size_t)b * 2304 * 512 + (size_t)m0 * 512;
  const unsigned short* Bb = Km + (size_t)b * 2304 * 512 + (size_t)n0 * 512;
  f32x4 acc[8][4] = {};
  gemm8_core<16, 32>(Ab, Bb, 512, 512, lds, acc);

  const int t = threadIdx.x;
  const int lane = t & 63, wid = t >> 6;
  const int wr = wid >> 2, wc = wid & 3;
  const int fr = lane & 15, fq = lane >> 4;
  unsigned short* Pp = P + (size_t)b * 2304 * 2304;
  const float SC = 0.044194173824159216f;
#pragma unroll
  for (int mf = 0; mf < 8; ++mf) {
    float rs[4] = {0.f, 0.f, 0.f, 0.f};
    const int rbase = m0 + wr * 128 + mf * 16 + fq * 4;
#pragma unroll
    for (int nf = 0; nf < 4; ++nf) {
      const int col = n0 + wc * 64 + nf * 16 + fr;
#pragma unroll
      for (int r = 0; r < 4; ++r) {
        const float e = __expf(acc[mf][nf][r] * SC - 4.0f);
        rs[r] += e;
        Pp[(size_t)(rbase + r) * 2304 + col] = f2bf(e);
      }
    }
#pragma unroll
    for (int r = 0; r < 4; ++r) {
      float s = rs[r];
#pragma unroll
      for (int o = 8; o >= 1; o >>= 1) s += __shfl_xor(s, o, 16);
      if (fr == 0) atomicAdd(&denom[(size_t)b * 2304 + rbase + r], s);
    }
  }
}

// ---- PV, 8-phase 256^2, K=2304 (NT=36, BK=64): out = (P@Vt^T)/denom ----
// swizzle: batch = lin&7; within batch, n fastest (P panel read once)
__global__ __launch_bounds__(512) void pv8_kernel(
    const unsigned short* __restrict__ P, const unsigned short* __restrict__ Vt,
    const float* __restrict__ denom, float* __restrict__ Out) {
  extern __shared__ unsigned short lds[];
  const int lin = blockIdx.x + 2 * (blockIdx.y + 9 * blockIdx.z);
  const int b = lin & 7, idx = lin >> 3;       // idx in [0,18)
  const int byp = idx >> 1, bxp = idx & 1;
  const int m0 = byp * 256, n0 = bxp * 256;
  const unsigned short* Ab = P + (size_t)b * 2304 * 2304 + (size_t)m0 * 2304;
  const unsigned short* Bb = Vt + (size_t)b * 512 * 2304 + (size_t)n0 * 2304;
  f32x4 acc[8][4] = {};
  gemm8_core<36, 64>(Ab, Bb, 2304, 2304, lds, acc);

  const int t = threadIdx.x;
  const int lane = t & 63, wid = t >> 6;
  const int wr = wid >> 2, wc = wid & 3;
  const int fr = lane & 15, fq = lane >> 4;
  float* Cp = Out + (size_t)b * 2304 * 512;
  const float* dn = denom + (size_t)b * 2304;
#pragma unroll
  for (int mf = 0; mf < 8; ++mf) {
    const int rbase = m0 + wr * 128 + mf * 16 + fq * 4;
#pragma unroll
    for (int r = 0; r < 4; ++r) {
      const float inv = 1.0f / dn[rbase + r];
#pragma unroll
      for (int nf = 0; nf < 4; ++nf) {
        const int col = n0 + wc * 64 + nf * 16 + fr;
        Cp[(size_t)(rbase + r) * 512 + col] = acc[mf][nf][r] * inv;
      }
    }
  }
}

extern "C" void kernel_launch(void* const* d_in, const int* in_sizes, int n_in,
                              void* d_out, int out_size, void* d_ws, size_t ws_size,
                              hipStream_t stream) {
  const float* x  = (const float*)d_in[0];
  const float* xt = (const float*)d_in[1];
  const float* wq = (const float*)d_in[2];
  const float* bq = (const float*)d_in[3];
  const float* wk = (const float*)d_in[4];
  const float* bk = (const float*)d_in[5];
  const float* wv = (const float*)d_in[6];
  const float* bv = (const float*)d_in[7];
  float* out = (float*)d_out;
  unsigned short* ws = (unsigned short*)d_ws;

  unsigned short* Q    = ws;
  unsigned short* Kb   = ws + 9437184;
  unsigned short* Vt   = ws + 18874368;
  unsigned short* P    = ws + 28311552;   // 85MB region
  unsigned short* xs   = ws + 28311552;   // aliases P (dead before P written)
  unsigned short* xts  = ws + 42467328;
  unsigned short* wcat = ws + 56623104;   // wq|wk|wv contiguous (1536x768)
  float* bcat  = (float*)(ws + 57802752); // 1536 f32 (inside P region, dead early)
  float* denom = (float*)(ws + 70778880); // 18432 f32, after P

  static int attr_set = 0;
  if (!attr_set) {
    hipFuncSetAttribute((const void*)qkv8_kernel,
                        hipFuncAttributeMaxDynamicSharedMemorySize, 65536);
    hipFuncSetAttribute((const void*)scores8_kernel,
                        hipFuncAttributeMaxDynamicSharedMemorySize, 65536);
    hipFuncSetAttribute((const void*)pv8_kernel,
                        hipFuncAttributeMaxDynamicSharedMemorySize, 131072);
    attr_set = 1;
  }

  convw3_kernel<<<1152, 256, 0, stream>>>(wq, wk, wv, wcat);
  init_kernel<<<78, 256, 0, stream>>>(bq, bk, bv, denom, bcat);
  transpose_bf16_kernel<<<dim3(36, 12, 16), 256, 0, stream>>>(x, xt, xs, xts);

  // fused Q|K|V projection (8-phase 256^2, BK=32, 2 blocks/CU)
  qkv8_kernel<<<dim3(6, 9, 8), 512, 65536, stream>>>(xs, xts, wcat, bcat, Q, Kb, Vt);

  // P = exp(Q K^T / sqrt(D) - 4), denom[row] = sum_t P (BK=32, 2 blocks/CU)
  scores8_kernel<<<dim3(9, 9, 8), 512, 65536, stream>>>(Q, Kb, denom, P);

  // out = (P @ V) / denom[row] (8-phase 256^2, NT=36, BK=64)
  pv8_kernel<<<dim3(2, 9, 8), 512, 131072, stream>>>(P, Vt, denom, out);
}